// Round 1
// baseline (405.516 us; speedup 1.0000x reference)
//
#include <hip/hip_runtime.h>
#include <math.h>

// DTW loss: B=128 batches, L1=L2=512, D=16.
// One block (512 threads) per batch. Thread j owns column j.
// Per row i the recurrence val_j = min(val_{j-1} + c_j, a_j) is a (min,+)
// scan over pairs (C,A):  (C1,A1)∘(C2,A2) = (C1+C2, min(A1+C2, A2)).
// val_j = A-component of inclusive composition over [0..j].
// One __syncthreads per row; LDS wave totals double-buffered by row parity.

#define TL1 512
#define TL2 512
#define TD  16
#define TNB 128
#define BIGF 3.0e38f

__global__ __launch_bounds__(512, 1) void dtw_dp_kernel(const float* __restrict__ s1,
                                                        const float* __restrict__ s2,
                                                        float* __restrict__ ws) {
    const int b    = blockIdx.x;
    const int j    = threadIdx.x;   // column 0..511
    const int lane = j & 63;
    const int w    = j >> 6;        // wave 0..7

    __shared__ float wsC[2][8];
    __shared__ float wsA[2][8];

    // s2[b, j, :] -> registers
    const float* s2r = s2 + ((size_t)b * TL2 + j) * TD;
    float y[TD];
    #pragma unroll
    for (int k = 0; k < TD; k += 4) {
        float4 v = *reinterpret_cast<const float4*>(s2r + k);
        y[k] = v.x; y[k + 1] = v.y; y[k + 2] = v.z; y[k + 3] = v.w;
    }

    const float* s1b = s1 + (size_t)b * TL1 * TD;

    float prev     = 0.f;    // val of previous row at this thread
    float edgePrev = BIGF;   // val at last lane of previous wave, previous row

    for (int i = 0; i < TL1; ++i) {
        const int p = i & 1;

        // c = ||s1[b,i,:] - s2[b,j,:]||^2   (s1 row address is wave-uniform)
        const float* s1r = s1b + i * TD;
        float c = 0.f;
        #pragma unroll
        for (int k = 0; k < TD; ++k) {
            float d = s1r[k] - y[k];
            c = fmaf(d, d, c);
        }

        // m_j: row 0 -> only-left (m=0 at j=0, +inf elsewhere);
        // rows >=1: j==0 only-up, else min(up, diag)
        float m;
        if (i == 0) {
            m = (j == 0) ? 0.f : BIGF;
        } else {
            float pm = __shfl_up(prev, 1);
            if (lane == 0) pm = edgePrev;
            m = (j == 0) ? prev : fminf(prev, pm);
        }

        float A = m + c;   // a_j (BIGF + c stays ~3e38, no overflow to inf)
        float C = c;

        // in-wave inclusive pair scan (64 lanes, 6 steps)
        #pragma unroll
        for (int dlt = 1; dlt < 64; dlt <<= 1) {
            float Cu = __shfl_up(C, dlt);
            float Au = __shfl_up(A, dlt);
            if (lane >= dlt) {
                A = fminf(Au + C, A);   // use pre-update C
                C = Cu + C;
            }
        }

        if (lane == 63) { wsC[p][w] = C; wsA[p][w] = A; }
        __syncthreads();

        // prefix-composition over waves 0..w-1 (identity = (0, BIG))
        float Apre = BIGF;
        #pragma unroll
        for (int ww = 0; ww < 7; ++ww) {
            if (ww < w) {
                float Cw = wsC[p][ww];
                float Aw = wsA[p][ww];
                Apre = fminf(Apre + Cw, Aw);
            }
        }

        float val = fminf(Apre + C, A);  // w==0: Apre=BIG -> val = A
        prev      = val;
        edgePrev  = Apre;   // == val at last lane of previous wave (this row)
    }

    if (j == TL2 - 1) ws[b] = sqrtf(prev);
}

__global__ void dtw_reduce_kernel(const float* __restrict__ ws, float* __restrict__ out) {
    const int t = threadIdx.x;          // 64 threads
    float v = ws[t] + ws[t + 64];
    #pragma unroll
    for (int d2 = 32; d2 > 0; d2 >>= 1) v += __shfl_down(v, d2);
    if (t == 0) out[0] = v * (1.0f / TNB);
}

extern "C" void kernel_launch(void* const* d_in, const int* in_sizes, int n_in,
                              void* d_out, int out_size, void* d_ws, size_t ws_size,
                              hipStream_t stream) {
    const float* s1 = (const float*)d_in[0];
    const float* s2 = (const float*)d_in[1];
    float* ws  = (float*)d_ws;
    float* out = (float*)d_out;

    dtw_dp_kernel<<<TNB, 512, 0, stream>>>(s1, s2, ws);
    dtw_reduce_kernel<<<1, 64, 0, stream>>>(ws, out);
}